// Round 1
// baseline (87.978 us; speedup 1.0000x reference)
//
#include <hip/hip_runtime.h>
#include <math.h>

#define LL 4096
#define BB 2048
#define NT 256
#define KPT (LL / NT)   // 16 elements per thread, strided by NT

#define ALPHA 1.0f
#define BETA 0.5f

__device__ __forceinline__ float wredf(float v) {
#pragma unroll
    for (int o = 32; o > 0; o >>= 1) v += __shfl_down(v, o, 64);
    return v;
}
__device__ __forceinline__ int wredi(int v) {
#pragma unroll
    for (int o = 32; o > 0; o >>= 1) v += __shfl_down(v, o, 64);
    return v;
}

// Computes peak info for one signal resident in sX.
// Uses sP/sS as scratch (destroyed). On return:
//   cnt20 = per-thread count of distance-20 peaks (w=39 window max + strict local max)
//   m10   = bitmask (bit k -> position t + k*NT) of distance-10 peaks (w=19)
__device__ __forceinline__ void peaks_pass(const float* __restrict__ sX,
                                           float* __restrict__ sP,
                                           float* __restrict__ sS,
                                           int t, int& cnt20, unsigned& m10) {
    // log-doubling sliding max: T_k(i) = max over [i, min(i+2^k-1, LL-1)]
    // T1: sX -> sP (off 1); T2: sP -> sS (2); T3: sS -> sP (4);
    // T4: sP -> sS (8)  [covers 16]; T5: sS -> sP (16) [covers 32]
    {
#pragma unroll
        for (int k = 0; k < KPT; ++k) {
            int i = t + k * NT;
            float v = sX[i];
            if (i + 1 < LL) v = fmaxf(v, sX[i + 1]);
            sP[i] = v;
        }
        __syncthreads();
#pragma unroll
        for (int k = 0; k < KPT; ++k) {
            int i = t + k * NT;
            float v = sP[i];
            if (i + 2 < LL) v = fmaxf(v, sP[i + 2]);
            sS[i] = v;
        }
        __syncthreads();
#pragma unroll
        for (int k = 0; k < KPT; ++k) {
            int i = t + k * NT;
            float v = sS[i];
            if (i + 4 < LL) v = fmaxf(v, sS[i + 4]);
            sP[i] = v;
        }
        __syncthreads();
#pragma unroll
        for (int k = 0; k < KPT; ++k) {
            int i = t + k * NT;
            float v = sP[i];
            if (i + 8 < LL) v = fmaxf(v, sP[i + 8]);
            sS[i] = v;   // T4 (16-wide) in sS
        }
        __syncthreads();
#pragma unroll
        for (int k = 0; k < KPT; ++k) {
            int i = t + k * NT;
            float v = sS[i];
            if (i + 16 < LL) v = fmaxf(v, sS[i + 16]);
            sP[i] = v;   // T5 (32-wide) in sP
        }
        __syncthreads();
    }

    cnt20 = 0;
    m10 = 0u;
#pragma unroll
    for (int k = 0; k < KPT; ++k) {
        int i = t + k * NT;
        if (i < 1 || i > LL - 2) continue;
        float xi = sX[i];
        // strict local max (interior only; ends padded False)
        if (!(xi > sX[i - 1] && xi > sX[i + 1])) continue;

        // pooled for w=19 (distance 10): window [i-9, i+9]
        float p19;
        {
            int l = i - 9;
            if (l < 0) {
                p19 = xi;
                for (int j = 0; j <= i + 9; ++j) p19 = fmaxf(p19, sX[j]);
            } else {
                p19 = fmaxf(sS[l], sS[l + 3]);   // T4 pair covers [l, l+18], right auto-clipped
            }
        }
        // pooled for w=39 (distance 20): window [i-19, i+19]
        float p39;
        {
            int l = i - 19;
            if (l < 0) {
                p39 = xi;
                for (int j = 0; j <= i + 19; ++j) p39 = fmaxf(p39, sX[j]);
            } else {
                p39 = fmaxf(sP[l], sP[l + 7]);   // T5 pair covers [l, l+38], right auto-clipped
            }
        }
        if (xi >= p39) cnt20++;
        if (xi >= p19) m10 |= (1u << k);
    }
    __syncthreads();   // protect sP/sS before caller reuses them
}

__global__ __launch_bounds__(NT, 1) void row_kernel(const float* __restrict__ gA,
                                                    const float* __restrict__ gB,
                                                    float4* __restrict__ rowout) {
    __shared__ float sA[LL];
    __shared__ float sB[LL];
    __shared__ float sP[LL];
    __shared__ float sS[LL];
    __shared__ float redf[4][5];
    __shared__ int   redi[4][2];

    const int b = blockIdx.x;
    const int t = threadIdx.x;
    const float4* a4 = (const float4*)(gA + (size_t)b * LL);
    const float4* b4 = (const float4*)(gB + (size_t)b * LL);

    float se = 0.f, dt = 0.f, na = 0.f, nb = 0.f;
#pragma unroll
    for (int k = 0; k < KPT / 4; ++k) {
        int i4 = t + k * NT;
        float4 va = a4[i4];
        float4 vb = b4[i4];
        ((float4*)sA)[i4] = va;
        ((float4*)sB)[i4] = vb;
        float dx = va.x - vb.x, dy = va.y - vb.y, dz = va.z - vb.z, dw = va.w - vb.w;
        se += dx * dx + dy * dy + dz * dz + dw * dw;
        dt += va.x * vb.x + va.y * vb.y + va.z * vb.z + va.w * vb.w;
        na += va.x * va.x + va.y * va.y + va.z * va.z + va.w * va.w;
        nb += vb.x * vb.x + vb.y * vb.y + vb.z * vb.z + vb.w * vb.w;
    }
    __syncthreads();

    int cntA, cntB;
    unsigned mA, mB;
    peaks_pass(sA, sP, sS, t, cntA, mA);
    peaks_pass(sB, sP, sS, t, cntB, mB);

    // peak-to-peak squared error at aligned positions (strided layout matches per-thread bits)
    float p2p = 0.f;
#pragma unroll
    for (int k = 0; k < KPT; ++k) {
        unsigned ba = (mA >> k) & 1u, bb = (mB >> k) & 1u;
        if (ba | bb) {
            int i = t + k * NT;
            float av = ba ? sA[i] : 0.f;
            float bv = bb ? sB[i] : 0.f;
            float d = av - bv;
            p2p += d * d;
        }
    }

    // block reduction
    se = wredf(se); dt = wredf(dt); na = wredf(na); nb = wredf(nb); p2p = wredf(p2p);
    int ca = wredi(cntA), cb = wredi(cntB);
    int w = t >> 6, lane = t & 63;
    if (lane == 0) {
        redf[w][0] = se; redf[w][1] = dt; redf[w][2] = na; redf[w][3] = nb; redf[w][4] = p2p;
        redi[w][0] = ca; redi[w][1] = cb;
    }
    __syncthreads();
    if (t == 0) {
        float tse = 0, tdt = 0, tna = 0, tnb = 0, tp2p = 0;
        int tca = 0, tcb = 0;
        for (int i = 0; i < NT / 64; ++i) {
            tse += redf[i][0]; tdt += redf[i][1]; tna += redf[i][2];
            tnb += redf[i][3]; tp2p += redf[i][4];
            tca += redi[i][0]; tcb += redi[i][1];
        }
        float mse_i = tse / (float)LL;
        float cos_i = tdt / (sqrtf(tna) * sqrtf(tnb));
        float p2p_i = tp2p / (float)LL;
        float custom_i = (tca != tcb) ? (mse_i * ALPHA) : (p2p_i * BETA);
        rowout[b] = make_float4(mse_i, cos_i, p2p_i, custom_i);
    }
}

__global__ __launch_bounds__(NT) void reduce_kernel(const float4* __restrict__ rows,
                                                    float* __restrict__ out) {
    __shared__ float red[4][4];
    float sx = 0.f, sy = 0.f, sz = 0.f, sw = 0.f;
    for (int r = threadIdx.x; r < BB; r += NT) {
        float4 v = rows[r];
        sx += v.x; sy += v.y; sz += v.z; sw += v.w;
    }
    sx = wredf(sx); sy = wredf(sy); sz = wredf(sz); sw = wredf(sw);
    int w = threadIdx.x >> 6, lane = threadIdx.x & 63;
    if (lane == 0) { red[w][0] = sx; red[w][1] = sy; red[w][2] = sz; red[w][3] = sw; }
    __syncthreads();
    if (threadIdx.x == 0) {
        float ax = 0, ay = 0, az = 0, aw = 0;
        for (int i = 0; i < NT / 64; ++i) {
            ax += red[i][0]; ay += red[i][1]; az += red[i][2]; aw += red[i][3];
        }
        float mse = ax / (float)BB;
        out[0] = mse + aw;          // total_loss = mse_loss + custom_loss
        out[1] = ay / (float)BB;    // mean cosine similarity
        out[2] = az;                // p2p_loss
        out[3] = mse;               // mse_loss
    }
}

extern "C" void kernel_launch(void* const* d_in, const int* in_sizes, int n_in,
                              void* d_out, int out_size, void* d_ws, size_t ws_size,
                              hipStream_t stream) {
    const float* inA = (const float*)d_in[0];   // in_signal
    const float* inB = (const float*)d_in[1];   // ref_signal
    float* out = (float*)d_out;
    float4* rows = (float4*)d_ws;               // 2048 * 16 B = 32 KiB

    hipLaunchKernelGGL(row_kernel, dim3(BB), dim3(NT), 0, stream, inA, inB, rows);
    hipLaunchKernelGGL(reduce_kernel, dim3(1), dim3(NT), 0, stream, rows, out);
}

// Round 2
// 45.202 us; speedup vs baseline: 1.9463x; 1.9463x over previous
//
#include <hip/hip_runtime.h>
#include <math.h>

#define LL 4096
#define BB 2048
#define NT 256
#define CH 16                    // contiguous elements per thread; NT*CH == LL
#define PAD_IDX(d) ((d) + ((d) >> 4))   // 16 -> 17 stride padding (conflict-free writes)
#define SPSZ (LL + (LL >> 4))    // 4352 dwords = 17 KB per array

#define ALPHA 1.0f
#define BETA 0.5f

__device__ __forceinline__ float wredf(float v) {
#pragma unroll
    for (int o = 32; o > 0; o >>= 1) v += __shfl_down(v, o, 64);
    return v;
}
__device__ __forceinline__ int wredi(int v) {
#pragma unroll
    for (int o = 32; o > 0; o >>= 1) v += __shfl_down(v, o, 64);
    return v;
}

__global__ __launch_bounds__(NT, 4) void row_kernel(const float* __restrict__ gA,
                                                    const float* __restrict__ gB,
                                                    float4* __restrict__ rowout) {
    // S[i] = max(x[i .. chunk_end(i)]), P[i] = max(x[chunk_start(i) .. i]),
    // chunks of 16 aligned; padded stride 17 for bank-conflict-free writes.
    __shared__ float sS[SPSZ];
    __shared__ float sP[SPSZ];
    __shared__ float redf[NT / 64][5];
    __shared__ int   redi[NT / 64][2];

    const int b = blockIdx.x;
    const int t = threadIdx.x;
    const float* rowA = gA + (size_t)b * LL;
    const float* rowB = gB + (size_t)b * LL;
    const int base = t * CH;

    // ---- load both chunks straight to registers (contiguous 64 B per thread) ----
    float xA[CH], xB[CH];
    {
        const float4* a4 = (const float4*)rowA;
        const float4* b4 = (const float4*)rowB;
#pragma unroll
        for (int k = 0; k < CH / 4; ++k) {
            float4 v = a4[t * (CH / 4) + k];
            xA[4 * k + 0] = v.x; xA[4 * k + 1] = v.y; xA[4 * k + 2] = v.z; xA[4 * k + 3] = v.w;
            float4 u = b4[t * (CH / 4) + k];
            xB[4 * k + 0] = u.x; xB[4 * k + 1] = u.y; xB[4 * k + 2] = u.z; xB[4 * k + 3] = u.w;
        }
    }
    // chunk-boundary neighbors (interior-only peaks, so edges unused)
    float aL = (t > 0)      ? rowA[base - 1]  : 0.f;
    float aR = (t < NT - 1) ? rowA[base + CH] : 0.f;
    float bL = (t > 0)      ? rowB[base - 1]  : 0.f;
    float bR = (t < NT - 1) ? rowB[base + CH] : 0.f;

    // ---- fused row stats ----
    float se = 0.f, dt = 0.f, na = 0.f, nb = 0.f;
#pragma unroll
    for (int j = 0; j < CH; ++j) {
        float d = xA[j] - xB[j];
        se += d * d;
        dt += xA[j] * xB[j];
        na += xA[j] * xA[j];
        nb += xB[j] * xB[j];
    }

    // ---- per-signal: in-register prefix/suffix max scan, write S/P to LDS ----
    auto scan_write = [&](const float (&x)[CH]) {
        float pp[CH], ss[CH];
        pp[0] = x[0];
#pragma unroll
        for (int j = 1; j < CH; ++j) pp[j] = fmaxf(pp[j - 1], x[j]);
        ss[CH - 1] = x[CH - 1];
#pragma unroll
        for (int j = CH - 2; j >= 0; --j) ss[j] = fmaxf(ss[j + 1], x[j]);
        const int pb = 17 * t;   // PAD_IDX(base)
#pragma unroll
        for (int j = 0; j < CH; ++j) {
            sP[pb + j] = pp[j];
            sS[pb + j] = ss[j];
        }
    };

    // ---- evaluate peaks: strict local max + centered-window max via S/P ----
    auto eval = [&](const float (&x)[CH], float xm1, float xp1, int& cnt20, unsigned& m10) {
        cnt20 = 0; m10 = 0u;
#pragma unroll
        for (int j = 0; j < CH; ++j) {
            int i = base + j;
            if (i == 0 || i == LL - 1) continue;         // interior only
            float xi = x[j];
            float xl = (j > 0)      ? x[j - 1] : xm1;
            float xr = (j < CH - 1) ? x[j + 1] : xp1;
            if (!(xi > xl && xi > xr)) continue;
            // w = 19 (distance 10): window [i-9, i+9] clipped
            {
                int l = i - 9;  if (l < 0) l = 0;
                int r = i + 9;  if (r > LL - 1) r = LL - 1;
                int ca = l >> 4, cb = r >> 4;
                float pooled;
                if (ca == cb) {
                    // only happens clipped at row edges: l==chunk start or r==chunk end
                    pooled = (l == (ca << 4)) ? sP[PAD_IDX(r)] : sS[PAD_IDX(l)];
                } else {
                    pooled = fmaxf(sS[PAD_IDX(l)], sP[PAD_IDX(r)]);
                    if (ca + 1 < cb) pooled = fmaxf(pooled, sP[17 * (ca + 1) + 15]);
                }
                if (xi >= pooled) m10 |= (1u << j);
            }
            // w = 39 (distance 20): window [i-19, i+19] clipped (always spans >=2 chunks)
            {
                int l = i - 19; if (l < 0) l = 0;
                int r = i + 19; if (r > LL - 1) r = LL - 1;
                int ca = l >> 4, cb = r >> 4;
                float pooled = fmaxf(sS[PAD_IDX(l)], sP[PAD_IDX(r)]);
                if (ca + 1 < cb) pooled = fmaxf(pooled, sP[17 * (ca + 1) + 15]);
                if (ca + 2 < cb) pooled = fmaxf(pooled, sP[17 * (ca + 2) + 15]);
                if (xi >= pooled) cnt20++;
            }
        }
    };

    int cntA, cntB;
    unsigned mA, mB;

    scan_write(xA);
    __syncthreads();
    eval(xA, aL, aR, cntA, mA);
    __syncthreads();                  // S/P about to be overwritten
    scan_write(xB);
    __syncthreads();
    eval(xB, bL, bR, cntB, mB);

    // peak-to-peak squared error (positions aligned per thread)
    float p2p = 0.f;
#pragma unroll
    for (int j = 0; j < CH; ++j) {
        float av = ((mA >> j) & 1u) ? xA[j] : 0.f;
        float bv = ((mB >> j) & 1u) ? xB[j] : 0.f;
        float d = av - bv;
        p2p += d * d;
    }

    // ---- block reduction ----
    se = wredf(se); dt = wredf(dt); na = wredf(na); nb = wredf(nb); p2p = wredf(p2p);
    int ca = wredi(cntA), cb = wredi(cntB);
    int w = t >> 6, lane = t & 63;
    if (lane == 0) {
        redf[w][0] = se; redf[w][1] = dt; redf[w][2] = na; redf[w][3] = nb; redf[w][4] = p2p;
        redi[w][0] = ca; redi[w][1] = cb;
    }
    __syncthreads();
    if (t == 0) {
        float tse = 0, tdt = 0, tna = 0, tnb = 0, tp2p = 0;
        int tca = 0, tcb = 0;
        for (int i = 0; i < NT / 64; ++i) {
            tse += redf[i][0]; tdt += redf[i][1]; tna += redf[i][2];
            tnb += redf[i][3]; tp2p += redf[i][4];
            tca += redi[i][0]; tcb += redi[i][1];
        }
        float mse_i = tse / (float)LL;
        float cos_i = tdt / (sqrtf(tna) * sqrtf(tnb));
        float p2p_i = tp2p / (float)LL;
        float custom_i = (tca != tcb) ? (mse_i * ALPHA) : (p2p_i * BETA);
        rowout[b] = make_float4(mse_i, cos_i, p2p_i, custom_i);
    }
}

__global__ __launch_bounds__(NT) void reduce_kernel(const float4* __restrict__ rows,
                                                    float* __restrict__ out) {
    __shared__ float red[NT / 64][4];
    float sx = 0.f, sy = 0.f, sz = 0.f, sw = 0.f;
    for (int r = threadIdx.x; r < BB; r += NT) {
        float4 v = rows[r];
        sx += v.x; sy += v.y; sz += v.z; sw += v.w;
    }
    sx = wredf(sx); sy = wredf(sy); sz = wredf(sz); sw = wredf(sw);
    int w = threadIdx.x >> 6, lane = threadIdx.x & 63;
    if (lane == 0) { red[w][0] = sx; red[w][1] = sy; red[w][2] = sz; red[w][3] = sw; }
    __syncthreads();
    if (threadIdx.x == 0) {
        float ax = 0, ay = 0, az = 0, aw = 0;
        for (int i = 0; i < NT / 64; ++i) {
            ax += red[i][0]; ay += red[i][1]; az += red[i][2]; aw += red[i][3];
        }
        float mse = ax / (float)BB;
        out[0] = mse + aw;          // total_loss = mse_loss + custom_loss
        out[1] = ay / (float)BB;    // mean cosine similarity
        out[2] = az;                // p2p_loss
        out[3] = mse;               // mse_loss
    }
}

extern "C" void kernel_launch(void* const* d_in, const int* in_sizes, int n_in,
                              void* d_out, int out_size, void* d_ws, size_t ws_size,
                              hipStream_t stream) {
    const float* inA = (const float*)d_in[0];   // in_signal
    const float* inB = (const float*)d_in[1];   // ref_signal
    float* out = (float*)d_out;
    float4* rows = (float4*)d_ws;               // 2048 * 16 B = 32 KiB scratch

    hipLaunchKernelGGL(row_kernel, dim3(BB), dim3(NT), 0, stream, inA, inB, rows);
    hipLaunchKernelGGL(reduce_kernel, dim3(1), dim3(NT), 0, stream, rows, out);
}

// Round 3
// 34.038 us; speedup vs baseline: 2.5847x; 1.3280x over previous
//
#include <hip/hip_runtime.h>
#include <math.h>

#define LL 4096
#define BB 2048
#define NT 512
#define CH 8                      // contiguous elements per thread; NT*CH == LL
#define ALPHA 1.0f
#define BETA 0.5f
#define NEG_INF (-__builtin_inff())
#define POS_INF (__builtin_inff())

// Padded LDS layout: logical position i in [-24, LL+23] lives at i + (i>>3) + 27.
// Identity: IDX(8t + d) == 9t + (d + (d>>3) + 27)  -> with base = arr + 9t, every
// offset the eval needs is a compile-time immediate (d is constexpr per unrolled j).
#define SPSZ 4672                 // > IDX(LL+23) = 4660

__device__ __forceinline__ float wredf(float v) {
#pragma unroll
    for (int o = 32; o > 0; o >>= 1) v += __shfl_down(v, o, 64);
    return v;
}
__device__ __forceinline__ int wredi(int v) {
#pragma unroll
    for (int o = 32; o > 0; o >>= 1) v += __shfl_down(v, o, 64);
    return v;
}

__global__ __launch_bounds__(NT, 8) void row_kernel(const float* __restrict__ gA,
                                                    const float* __restrict__ gB,
                                                    float4* __restrict__ rowout) {
    __shared__ float sS[SPSZ];    // suffix-max within 8-aligned chunk (+ -inf margins)
    __shared__ float sP[SPSZ];    // prefix-max within 8-aligned chunk (+ -inf margins)
    __shared__ float redf[NT / 64][5];
    __shared__ int   redi[NT / 64][2];

    const int b = blockIdx.x;
    const int t = threadIdx.x;
    const int base = t * CH;
    float* const Sb = sS + 9 * t;       // Sb[d + (d>>3) + 27] == sS[IDX(base + d)]
    float* const Pb = sP + 9 * t;
    const float* rowA = gA + (size_t)b * LL;
    const float* rowB = gB + (size_t)b * LL;

    // ---- load both chunks straight to registers (32 B contiguous per thread) ----
    float xA[CH], xB[CH];
    {
        const float4* a4 = (const float4*)rowA;
        const float4* b4 = (const float4*)rowB;
#pragma unroll
        for (int k = 0; k < CH / 4; ++k) {
            float4 v = a4[t * (CH / 4) + k];
            xA[4 * k + 0] = v.x; xA[4 * k + 1] = v.y; xA[4 * k + 2] = v.z; xA[4 * k + 3] = v.w;
            float4 u = b4[t * (CH / 4) + k];
            xB[4 * k + 0] = u.x; xB[4 * k + 1] = u.y; xB[4 * k + 2] = u.z; xB[4 * k + 3] = u.w;
        }
    }

    // ---- fused row stats ----
    float se = 0.f, dt = 0.f, na = 0.f, nb = 0.f;
#pragma unroll
    for (int j = 0; j < CH; ++j) {
        float d = xA[j] - xB[j];
        se += d * d;
        dt += xA[j] * xB[j];
        na += xA[j] * xA[j];
        nb += xB[j] * xB[j];
    }

    // ---- -inf margins (logical i in [-24,-1] and [LL, LL+23]); written once ----
    if (t < 24) {
        int i = t - 24;
        int p = i + (i >> 3) + 27;
        sS[p] = NEG_INF; sP[p] = NEG_INF;
    } else if (t >= NT - 24) {
        int i = LL + (t - (NT - 24));
        int p = i + (i >> 3) + 27;
        sS[p] = NEG_INF; sP[p] = NEG_INF;
    }

    // ---- per-signal: scan -> LDS, barrier, branchless eval (all imm offsets) ----
    auto process = [&](const float (&x)[CH], int& cnt20, unsigned& m10) {
        float pp[CH], ss[CH];
        pp[0] = x[0];
#pragma unroll
        for (int j = 1; j < CH; ++j) pp[j] = fmaxf(pp[j - 1], x[j]);
        ss[CH - 1] = x[CH - 1];
#pragma unroll
        for (int j = CH - 2; j >= 0; --j) ss[j] = fmaxf(ss[j + 1], x[j]);
#pragma unroll
        for (int j = 0; j < CH; ++j) {
            Pb[j + 27] = pp[j];
            Sb[j + 27] = ss[j];
        }
        const float cmax = pp[CH - 1];
        __syncthreads();

        // neighbor chunk maxes: C(t+k) = Pb[9k + 34]  (margins give -inf at edges)
        const float Cm2 = Pb[16], Cm1 = Pb[25], Cp1 = Pb[43], Cp2 = Pb[52];
        const float f1 = fmaxf(Cm1, cmax);          // w19 middles, j==0: {t-1,t}
        const float f2 = fmaxf(cmax, Cp1);          // w19 middles, j==7: {t,t+1}
        const float g2 = fmaxf(f1, Cp1);            // w39 middles, j=3..4: {t-1,t,t+1}
        const float g1 = fmaxf(g2, Cm2);            // w39 middles, j=0..2: {t-2..t+1}
        const float g3 = fmaxf(g2, Cp2);            // w39 middles, j=5..7: {t-1..t+2}
        const float xm1 = (t == 0)      ? POS_INF : Sb[25];   // x[base-1]
        const float xp1 = (t == NT - 1) ? POS_INF : Pb[36];   // x[base+8]

        cnt20 = 0; m10 = 0u;
#pragma unroll
        for (int j = 0; j < CH; ++j) {
            float xi = x[j];
            float xl = (j > 0)      ? x[j - 1] : xm1;
            float xr = (j < CH - 1) ? x[j + 1] : xp1;
            bool lm = (xi > xl) && (xi > xr);
            // all offsets constant-fold: d + (d>>3) + 27 with d constexpr
            float a19 = Sb[(j - 9)  + ((j - 9)  >> 3) + 27];
            float b19 = Pb[(j + 9)  + ((j + 9)  >> 3) + 27];
            float a39 = Sb[(j - 19) + ((j - 19) >> 3) + 27];
            float b39 = Pb[(j + 19) + ((j + 19) >> 3) + 27];
            float mid19 = (j == 0) ? f1 : ((j == CH - 1) ? f2 : cmax);
            float mid39 = (j <= 2) ? g1 : ((j <= 4) ? g2 : g3);
            float p19 = fmaxf(fmaxf(a19, b19), mid19);
            float p39 = fmaxf(fmaxf(a39, b39), mid39);
            if (lm && xi >= p19) m10 |= (1u << j);
            if (lm && xi >= p39) cnt20++;
        }
    };

    int cntA, cntB;
    unsigned mA, mB;
    process(xA, cntA, mA);
    __syncthreads();              // evalA reads done before scanB overwrites
    process(xB, cntB, mB);

    // ---- peak-to-peak squared error (positions aligned per thread) ----
    float p2p = 0.f;
#pragma unroll
    for (int j = 0; j < CH; ++j) {
        float av = ((mA >> j) & 1u) ? xA[j] : 0.f;
        float bv = ((mB >> j) & 1u) ? xB[j] : 0.f;
        float d = av - bv;
        p2p += d * d;
    }

    // ---- block reduction ----
    se = wredf(se); dt = wredf(dt); na = wredf(na); nb = wredf(nb); p2p = wredf(p2p);
    int ca = wredi(cntA), cb = wredi(cntB);
    int w = t >> 6, lane = t & 63;
    if (lane == 0) {
        redf[w][0] = se; redf[w][1] = dt; redf[w][2] = na; redf[w][3] = nb; redf[w][4] = p2p;
        redi[w][0] = ca; redi[w][1] = cb;
    }
    __syncthreads();
    if (t == 0) {
        float tse = 0, tdt = 0, tna = 0, tnb = 0, tp2p = 0;
        int tca = 0, tcb = 0;
        for (int i = 0; i < NT / 64; ++i) {
            tse += redf[i][0]; tdt += redf[i][1]; tna += redf[i][2];
            tnb += redf[i][3]; tp2p += redf[i][4];
            tca += redi[i][0]; tcb += redi[i][1];
        }
        float mse_i = tse / (float)LL;
        float cos_i = tdt / (sqrtf(tna) * sqrtf(tnb));
        float p2p_i = tp2p / (float)LL;
        float custom_i = (tca != tcb) ? (mse_i * ALPHA) : (p2p_i * BETA);
        rowout[b] = make_float4(mse_i, cos_i, p2p_i, custom_i);
    }
}

__global__ __launch_bounds__(256) void reduce_kernel(const float4* __restrict__ rows,
                                                     float* __restrict__ out) {
    __shared__ float red[4][4];
    float sx = 0.f, sy = 0.f, sz = 0.f, sw = 0.f;
    for (int r = threadIdx.x; r < BB; r += 256) {
        float4 v = rows[r];
        sx += v.x; sy += v.y; sz += v.z; sw += v.w;
    }
    sx = wredf(sx); sy = wredf(sy); sz = wredf(sz); sw = wredf(sw);
    int w = threadIdx.x >> 6, lane = threadIdx.x & 63;
    if (lane == 0) { red[w][0] = sx; red[w][1] = sy; red[w][2] = sz; red[w][3] = sw; }
    __syncthreads();
    if (threadIdx.x == 0) {
        float ax = 0, ay = 0, az = 0, aw = 0;
        for (int i = 0; i < 4; ++i) {
            ax += red[i][0]; ay += red[i][1]; az += red[i][2]; aw += red[i][3];
        }
        float mse = ax / (float)BB;
        out[0] = mse + aw;          // total_loss = mse_loss + custom_loss
        out[1] = ay / (float)BB;    // mean cosine similarity
        out[2] = az;                // p2p_loss
        out[3] = mse;               // mse_loss
    }
}

extern "C" void kernel_launch(void* const* d_in, const int* in_sizes, int n_in,
                              void* d_out, int out_size, void* d_ws, size_t ws_size,
                              hipStream_t stream) {
    const float* inA = (const float*)d_in[0];   // in_signal
    const float* inB = (const float*)d_in[1];   // ref_signal
    float* out = (float*)d_out;
    float4* rows = (float4*)d_ws;               // 2048 * 16 B scratch, fully rewritten each call

    hipLaunchKernelGGL(row_kernel, dim3(BB), dim3(NT), 0, stream, inA, inB, rows);
    hipLaunchKernelGGL(reduce_kernel, dim3(1), dim3(256), 0, stream, rows, out);
}